// Round 6
// baseline (290.409 us; speedup 1.0000x reference)
//
#include <hip/hip_runtime.h>
#include <hip/hip_bf16.h>
#include <stdint.h>

#define DDIM 1024
#define NEXP 8
#define SEG  16384   // per-expert token capacity (worst case: every token picks it)

typedef __attribute__((ext_vector_type(8))) short bf16x8;
typedef __attribute__((ext_vector_type(4))) float f32x4;
typedef __attribute__((ext_vector_type(8))) unsigned short u16x8;

#define AS1 __attribute__((address_space(1)))
#define AS3 __attribute__((address_space(3)))

__device__ __forceinline__ unsigned short f2bf(float f) {
    union { float f; unsigned int u; } v; v.f = f;
    unsigned int u = v.u;
    return (unsigned short)((u + 0x7FFFu + ((u >> 16) & 1u)) >> 16);
}
__device__ __forceinline__ float bf2f(unsigned short h) {
    union { unsigned int u; float f; } v; v.u = ((unsigned int)h) << 16;
    return v.f;
}

// ---------------- Kernel A (fused): We fp32->bf16 convert + gating/routing ----
__global__ __launch_bounds__(512) void prep(
    const float* __restrict__ x, const float* __restrict__ Wg,
    const float* __restrict__ bg, const float* __restrict__ We,
    unsigned short* __restrict__ xb, unsigned short* __restrict__ web,
    int* __restrict__ cnt, int* __restrict__ tok_list,
    float* __restrict__ gate_list) {

    __shared__ int   se[64];   // entry = local_token*2 + slot
    __shared__ float sg[64];

    if (blockIdx.x >= 512) {
        size_t idx = ((size_t)(blockIdx.x - 512) * 512 + threadIdx.x) * 8;
        const f32x4* p = (const f32x4*)(We + idx);
        f32x4 a = __builtin_nontemporal_load(p);
        f32x4 b = __builtin_nontemporal_load(p + 1);
        u16x8 h;
        h[0] = f2bf(a[0]); h[1] = f2bf(a[1]); h[2] = f2bf(a[2]); h[3] = f2bf(a[3]);
        h[4] = f2bf(b[0]); h[5] = f2bf(b[1]); h[6] = f2bf(b[2]); h[7] = f2bf(b[3]);
        *(u16x8*)(web + idx) = h;
        return;
    }

    int wave = threadIdx.x >> 6, lane = threadIdx.x & 63;
    int tbase = blockIdx.x * 32;

#pragma unroll
    for (int i = 0; i < 4; i++) {
        int lt = wave * 4 + i;
        int t = tbase + lt;
        const float* xr = x + (size_t)t * DDIM;
        int c0 = lane * 8;

        float4 v0 = ((const float4*)(xr + c0))[0];
        float4 v1 = ((const float4*)(xr + c0))[1];
        float4 v2 = ((const float4*)(xr + c0 + 512))[0];
        float4 v3 = ((const float4*)(xr + c0 + 512))[1];

        u16x8 h0, h1;
        h0[0] = f2bf(v0.x); h0[1] = f2bf(v0.y); h0[2] = f2bf(v0.z); h0[3] = f2bf(v0.w);
        h0[4] = f2bf(v1.x); h0[5] = f2bf(v1.y); h0[6] = f2bf(v1.z); h0[7] = f2bf(v1.w);
        h1[0] = f2bf(v2.x); h1[1] = f2bf(v2.y); h1[2] = f2bf(v2.z); h1[3] = f2bf(v2.w);
        h1[4] = f2bf(v3.x); h1[5] = f2bf(v3.y); h1[6] = f2bf(v3.z); h1[7] = f2bf(v3.w);
        *(u16x8*)(xb + (size_t)t * DDIM + c0) = h0;
        *(u16x8*)(xb + (size_t)t * DDIM + c0 + 512) = h1;

        float acc[NEXP];
#pragma unroll
        for (int e = 0; e < NEXP; e++) {
            const float* wr = Wg + e * DDIM;
            float4 w0 = ((const float4*)(wr + c0))[0];
            float4 w1 = ((const float4*)(wr + c0))[1];
            float4 w2 = ((const float4*)(wr + c0 + 512))[0];
            float4 w3 = ((const float4*)(wr + c0 + 512))[1];
            float s = v0.x*w0.x + v0.y*w0.y + v0.z*w0.z + v0.w*w0.w;
            s += v1.x*w1.x + v1.y*w1.y + v1.z*w1.z + v1.w*w1.w;
            s += v2.x*w2.x + v2.y*w2.y + v2.z*w2.z + v2.w*w2.w;
            s += v3.x*w3.x + v3.y*w3.y + v3.z*w3.z + v3.w*w3.w;
            acc[e] = s;
        }
#pragma unroll
        for (int e = 0; e < NEXP; e++) {
#pragma unroll
            for (int o = 32; o > 0; o >>= 1) acc[e] += __shfl_xor(acc[e], o, 64);
        }

        if (lane == 0) {
            float l1 = -1e30f, l2 = -1e30f; int e1 = 0, e2 = 0;
#pragma unroll
            for (int e = 0; e < NEXP; e++) {
                float le = acc[e] + bg[e];
                if (le > l1) { l2 = l1; e2 = e1; l1 = le; e1 = e; }
                else if (le > l2) { l2 = le; e2 = e; }
            }
            float g1 = 1.0f / (1.0f + __expf(l2 - l1));
            float g2 = 1.0f - g1;
            se[lt * 2]     = e1; sg[lt * 2]     = g1;
            se[lt * 2 + 1] = e2; sg[lt * 2 + 1] = g2;
        }
    }
    __syncthreads();

    if (threadIdx.x < NEXP) {
        int e = threadIdx.x;
        int k = 0;
#pragma unroll 8
        for (int i = 0; i < 64; i++) k += (se[i] == e);
        if (k) {
            int p = atomicAdd(cnt + e, k);
            for (int i = 0; i < 64; i++) {
                if (se[i] == e) {
                    tok_list[e * SEG + p]  = (tbase + (i >> 1)) * 2 + (i & 1);
                    gate_list[e * SEG + p] = sg[i];
                    p++;
                }
            }
        }
    }
}

// ---------------- Kernel C: per-expert gathered GEMM, bf16 MFMA ----------------
// LDS-traffic fix vs r5: 256x256 tile, 8 waves (2m x 4n), each wave 128x64
// (8x4 frags -> 42.7 FLOP per LDS byte vs 32 at 64x64). r1/r5's verified ring-3
// schedule: BK=32, 3 slots x (A[256][32]|B[256][32]) = 32KB/slot, 96KB total ->
// 1 block/CU, so __launch_bounds__(512,1) lifts the 256-reg cap (no spill).
// ONE s_barrier per K-tile, counted vmcnt(4) (4 stage-loads/wave/K-tile; next
// tile's loads stay in flight across the barrier). Rotation swizzle
// slot=(g+(row>>1))&3 with inverse rotation pre-applied to the per-lane GLOBAL
// source address (linear wave-uniform LDS dst for global_load_lds).
// Bijective XCD chunk swizzle over the 544-block grid (544 = 8 x 68): each XCD
// gets 17 consecutive m-tiles x 4 n-tiles -> A-panels stay L2-local.

__device__ __forceinline__ void stage_tile(const unsigned short* const* sp,
                                           unsigned short* lbase, int wave, int kt) {
    int ko = kt << 5;   // kt * 32 elements
#pragma unroll
    for (int j = 0; j < 4; ++j) {
        __builtin_amdgcn_global_load_lds(
            (const AS1 void*)(sp[j] + ko),
            (AS3 void*)(lbase + (wave * 4 + j) * 512),
            16, 0, 0);
    }
}

__device__ __forceinline__ void tile_mma(const unsigned short* ba, int aoff, int boff,
                                         f32x4 (&acc)[8][4]) {
    bf16x8 af[8], bf[4];
#pragma unroll
    for (int mi = 0; mi < 8; ++mi) af[mi] = *(const bf16x8*)(ba + aoff + mi * 512);
#pragma unroll
    for (int ni = 0; ni < 4; ++ni) bf[ni] = *(const bf16x8*)(ba + boff + ni * 512);
    __builtin_amdgcn_s_setprio(1);
#pragma unroll
    for (int mi = 0; mi < 8; ++mi)
#pragma unroll
        for (int ni = 0; ni < 4; ++ni)
            acc[mi][ni] = __builtin_amdgcn_mfma_f32_16x16x32_bf16(
                af[mi], bf[ni], acc[mi][ni], 0, 0, 0);
    __builtin_amdgcn_s_setprio(0);
}

template<bool STORE>
__global__ __launch_bounds__(512, 1) void moe_gemm(
    const unsigned short* __restrict__ xb, const unsigned short* __restrict__ web,
    const float* __restrict__ be, const int* __restrict__ cnt,
    const int* __restrict__ tok_list, const float* __restrict__ gate_list,
    unsigned short* __restrict__ Sb, float* __restrict__ outa) {

    extern __shared__ __align__(16) unsigned short lbuf[];  // 3 slots x 16384 el = 96 KB
    __shared__ int   tok_s[256];
    __shared__ float gate_s[256];

    // bijective XCD chunk swizzle: dispatch id -> logical tile id L
    int fid = blockIdx.x + blockIdx.y * 4;          // dispatch order (x fastest)
    int L = (fid & 7) * 68 + (fid >> 3);            // 544 = 8 XCDs x 68 chunk

    // exact-grid: find (expert, tile) from L via prefix over cnt
    int e = 0, c = 0, rem = L;
    while (e < NEXP) {
        c = cnt[e];
        int t_e = ((c + 255) >> 8) << 2;            // m-tiles * 4 n-tiles
        if (rem < t_e) break;
        rem -= t_e; e++;
    }
    if (e == NEXP) return;
    int m0 = (rem >> 2) << 8;
    int n0 = (rem & 3) << 8;

    int tid = threadIdx.x;
    int w = tid >> 6, lane = tid & 63;
    int wave_m = w >> 2, wave_n = w & 3;   // 2 x 4 wave grid, each owns 128x64

    if (tid < 256) {
        int r = m0 + tid;
        int rc = min(r, c - 1);
        tok_s[tid]  = tok_list[e * SEG + rc];
        gate_s[tid] = (r < c) ? gate_list[e * SEG + rc] : 0.0f;
    }
    __syncthreads();

    // LDS read offsets (elements); rotation slot for 16-aligned rows = (mrow>>1)&3
    int mrow = lane & 15, q = lane >> 4;
    int ksl  = ((q + (mrow >> 1)) & 3) << 3;
    int aoff = (wave_m * 128 + mrow) * 32 + ksl;          // + mi*512
    int boff = 8192 + (wave_n * 64 + mrow) * 32 + ksl;    // + ni*512

    // staging: chunk ch = w*4+j covers 16 rows; ch<16 -> A rows ch*16+sub;
    // ch>=16 -> B rows (ch-16)*16+sub; per-lane source granule pre-rotated.
    int g0  = ((lane & 3) - ((lane >> 3) & 3)) & 3;
    int sub = lane >> 2;
    const unsigned short* sp[4];
#pragma unroll
    for (int j = 0; j < 4; ++j) {
        int ch = w * 4 + j;
        int arow = (ch << 4) + sub;                 // ch<16: 0..255
        int brow = ((ch - 16) << 4) + sub;          // ch>=16: 0..255
        const unsigned short* pa = xb + (size_t)(tok_s[arow & 255] >> 1) * DDIM + g0 * 8;
        const unsigned short* pb = web + ((size_t)e << 20) +
                                   (size_t)(n0 + brow) * DDIM + g0 * 8;
        sp[j] = (ch < 16) ? pa : pb;
    }

    f32x4 acc[8][4];
#pragma unroll
    for (int mi = 0; mi < 8; ++mi)
#pragma unroll
        for (int ni = 0; ni < 4; ++ni) acc[mi][ni] = (f32x4){0.f, 0.f, 0.f, 0.f};

    // ---- prologue: stage K-tiles 0,1 (4 loads each per wave; 8 outstanding) ----
    stage_tile(sp, lbuf,         w, 0);
    stage_tile(sp, lbuf + 16384, w, 1);

    // ---- main loop: K-tiles 0..29, stage kt+2, wait vmcnt(4) (tile kt done,
    //      tile kt+1's 4 loads stay in flight across the barrier) ----
    for (int kb = 0; kb < 10; ++kb) {
#pragma unroll
        for (int u = 0; u < 3; ++u) {
            int kt = kb * 3 + u;
            asm volatile("s_waitcnt vmcnt(4)" ::: "memory");
            __builtin_amdgcn_s_barrier();
            asm volatile("" ::: "memory");
            stage_tile(sp, lbuf + ((u + 2) % 3) * 16384, w, kt + 2);
            tile_mma(lbuf + u * 16384, aoff, boff, acc);
        }
    }
    // ---- epilogue tiles 30 (slot 0) and 31 (slot 1) ----
    asm volatile("s_waitcnt vmcnt(4)" ::: "memory");
    __builtin_amdgcn_s_barrier();
    asm volatile("" ::: "memory");
    tile_mma(lbuf, aoff, boff, acc);

    asm volatile("s_waitcnt vmcnt(0)" ::: "memory");
    __builtin_amdgcn_s_barrier();
    asm volatile("" ::: "memory");
    tile_mma(lbuf + 16384, aoff, boff, acc);

    if (STORE) {
        // ---- two 128-row passes: stage C (gate*(acc+bias), bf16) via LDS ----
        __syncthreads();
#pragma unroll
        for (int p = 0; p < 2; ++p) {
            if (wave_m == p) {
#pragma unroll
                for (int ni = 0; ni < 4; ++ni) {
                    int col = wave_n * 64 + ni * 16 + mrow;   // tile-local col
                    float bias = be[e * DDIM + n0 + col];
                    int cg = col >> 3, cl = col & 7;
#pragma unroll
                    for (int mi = 0; mi < 8; ++mi) {
#pragma unroll
                        for (int r = 0; r < 4; ++r) {
                            int row = mi * 16 + q * 4 + r;    // pass-local 0..127
                            lbuf[row * 256 + ((cg ^ (row & 7)) << 3) + cl] =
                                f2bf(gate_s[p * 128 + row] * (acc[mi][ni][r] + bias));
                        }
                    }
                }
            }
            __syncthreads();
            // coalesced 16B stores: 128x32 granules / 512 threads = 8 iters
#pragma unroll
            for (int j = 0; j < 8; ++j) {
                int t = j * 512 + tid;
                int row = t >> 5, gc = t & 31;
                u16x8 vv = *(const u16x8*)&lbuf[row * 256 + ((gc ^ (row & 7)) << 3)];
                if (m0 + p * 128 + row < c)
                    *(u16x8*)(Sb + (size_t)tok_s[p * 128 + row] * DDIM + n0 + gc * 8) = vv;
            }
            __syncthreads();
        }
    } else {
        __syncthreads();
#pragma unroll
        for (int ni = 0; ni < 4; ++ni) {
            int col = n0 + wave_n * 64 + ni * 16 + mrow;
            float bias = be[e * DDIM + col];
#pragma unroll
            for (int mi = 0; mi < 8; ++mi) {
#pragma unroll
                for (int r = 0; r < 4; ++r) {
                    int rl = wave_m * 128 + mi * 16 + q * 4 + r;
                    if (m0 + rl < c)
                        atomicAdd(outa + (size_t)(tok_s[rl] >> 1) * DDIM + col,
                                  gate_s[rl] * (acc[mi][ni][r] + bias));
                }
            }
        }
    }
}

// ---------------- Kernel D: combine the two slot rows per token ----------------
__global__ void combine(const unsigned short* __restrict__ S, float* __restrict__ out) {
    size_t i = (size_t)blockIdx.x * 256 + threadIdx.x;
    size_t t = i >> 7;
    size_t g = i & 127;
    const u16x8* r0 = (const u16x8*)(S + t * 2 * DDIM) + g;
    const u16x8* r1 = (const u16x8*)(S + (t * 2 + 1) * DDIM) + g;
    u16x8 a = *r0;
    u16x8 b = *r1;
    f32x4 o0, o1;
#pragma unroll
    for (int k = 0; k < 4; k++) o0[k] = bf2f(a[k]) + bf2f(b[k]);
#pragma unroll
    for (int k = 0; k < 4; k++) o1[k] = bf2f(a[4 + k]) + bf2f(b[4 + k]);
    f32x4* op = (f32x4*)(out + t * DDIM + g * 8);
    __builtin_nontemporal_store(o0, op);
    __builtin_nontemporal_store(o1, op + 1);
}

extern "C" void kernel_launch(void* const* d_in, const int* in_sizes, int n_in,
                              void* d_out, int out_size, void* d_ws, size_t ws_size,
                              hipStream_t stream) {
    const float* x  = (const float*)d_in[0];
    const float* Wg = (const float*)d_in[1];
    const float* bg = (const float*)d_in[2];
    const float* We = (const float*)d_in[3];
    const float* be = (const float*)d_in[4];
    float* out = (float*)d_out;

    char* ws = (char*)d_ws;
    unsigned short* xb  = (unsigned short*)ws;                          // 32 MB
    unsigned short* web = (unsigned short*)(ws + 33554432);             // 16 MB
    int*   tok_list  = (int*)(ws + 33554432 + 16777216);                // 512 KB
    float* gate_list = (float*)(ws + 33554432 + 16777216 + 524288);     // 512 KB
    int*   cnt       = (int*)(ws + 33554432 + 16777216 + 1048576);      // 32 B
    unsigned short* S = (unsigned short*)(ws + 52428800);               // 67.1 MB

    const size_t NEED = 52428800ull + (size_t)32768 * DDIM * 2;         // ~119.5 MB

    // one-time opt-in for 96KB dynamic LDS
    static bool attr_done = false;
    if (!attr_done) {
        hipFuncSetAttribute(reinterpret_cast<const void*>(moe_gemm<true>),
                            hipFuncAttributeMaxDynamicSharedMemorySize, 98304);
        hipFuncSetAttribute(reinterpret_cast<const void*>(moe_gemm<false>),
                            hipFuncAttributeMaxDynamicSharedMemorySize, 98304);
        attr_done = true;
    }

    hipMemsetAsync(cnt, 0, NEXP * sizeof(int), stream);

    // 512 gating blocks + 2048 convert blocks in one dispatch
    prep<<<2560, 512, 0, stream>>>(x, Wg, bg, We, xb, web, cnt, tok_list, gate_list);

    if (ws_size >= NEED) {
        // grid = 4 n-tiles x 136 m-tiles = 544 blocks (136 = 32768/256 + 8 partials)
        moe_gemm<true><<<dim3(4, 136), 512, 98304, stream>>>(
            xb, web, be, cnt, tok_list, gate_list, S, nullptr);
        combine<<<8192, 256, 0, stream>>>(S, out);
    } else {
        hipMemsetAsync(d_out, 0, (size_t)out_size * sizeof(float), stream);
        moe_gemm<false><<<dim3(4, 136), 512, 98304, stream>>>(
            xb, web, be, cnt, tok_list, gate_list, nullptr, out);
    }
}

// Round 8
// 279.419 us; speedup vs baseline: 1.0393x; 1.0393x over previous
//
#include <hip/hip_runtime.h>
#include <hip/hip_bf16.h>
#include <stdint.h>

#define DDIM 1024
#define NEXP 8
#define SEG  16384   // per-expert token capacity (worst case: every token picks it)
#define CPAD 16      // cnt stride in ints: one 64B cache line per expert counter

typedef __attribute__((ext_vector_type(8))) short bf16x8;
typedef __attribute__((ext_vector_type(4))) float f32x4;
typedef __attribute__((ext_vector_type(8))) unsigned short u16x8;

#define AS1 __attribute__((address_space(1)))
#define AS3 __attribute__((address_space(3)))

__device__ __forceinline__ unsigned short f2bf(float f) {
    union { float f; unsigned int u; } v; v.f = f;
    unsigned int u = v.u;
    return (unsigned short)((u + 0x7FFFu + ((u >> 16) & 1u)) >> 16);
}
__device__ __forceinline__ float bf2f(unsigned short h) {
    union { unsigned int u; float f; } v; v.u = ((unsigned int)h) << 16;
    return v.f;
}

// ---------------- Kernel A (fused): We fp32->bf16 convert + gating/routing ----
__global__ __launch_bounds__(512) void prep(
    const float* __restrict__ x, const float* __restrict__ Wg,
    const float* __restrict__ bg, const float* __restrict__ We,
    unsigned short* __restrict__ xb, unsigned short* __restrict__ web,
    int* __restrict__ cnt, int* __restrict__ tok_list,
    float* __restrict__ gate_list) {

    __shared__ int   se[64];   // entry = local_token*2 + slot
    __shared__ float sg[64];

    if (blockIdx.x >= 512) {
        size_t idx = ((size_t)(blockIdx.x - 512) * 512 + threadIdx.x) * 8;
        const f32x4* p = (const f32x4*)(We + idx);
        f32x4 a = __builtin_nontemporal_load(p);
        f32x4 b = __builtin_nontemporal_load(p + 1);
        u16x8 h;
        h[0] = f2bf(a[0]); h[1] = f2bf(a[1]); h[2] = f2bf(a[2]); h[3] = f2bf(a[3]);
        h[4] = f2bf(b[0]); h[5] = f2bf(b[1]); h[6] = f2bf(b[2]); h[7] = f2bf(b[3]);
        *(u16x8*)(web + idx) = h;
        return;
    }

    int wave = threadIdx.x >> 6, lane = threadIdx.x & 63;
    int tbase = blockIdx.x * 32;

#pragma unroll
    for (int i = 0; i < 4; i++) {
        int lt = wave * 4 + i;
        int t = tbase + lt;
        const float* xr = x + (size_t)t * DDIM;
        int c0 = lane * 8;

        float4 v0 = ((const float4*)(xr + c0))[0];
        float4 v1 = ((const float4*)(xr + c0))[1];
        float4 v2 = ((const float4*)(xr + c0 + 512))[0];
        float4 v3 = ((const float4*)(xr + c0 + 512))[1];

        u16x8 h0, h1;
        h0[0] = f2bf(v0.x); h0[1] = f2bf(v0.y); h0[2] = f2bf(v0.z); h0[3] = f2bf(v0.w);
        h0[4] = f2bf(v1.x); h0[5] = f2bf(v1.y); h0[6] = f2bf(v1.z); h0[7] = f2bf(v1.w);
        h1[0] = f2bf(v2.x); h1[1] = f2bf(v2.y); h1[2] = f2bf(v2.z); h1[3] = f2bf(v2.w);
        h1[4] = f2bf(v3.x); h1[5] = f2bf(v3.y); h1[6] = f2bf(v3.z); h1[7] = f2bf(v3.w);
        *(u16x8*)(xb + (size_t)t * DDIM + c0) = h0;
        *(u16x8*)(xb + (size_t)t * DDIM + c0 + 512) = h1;

        float acc[NEXP];
#pragma unroll
        for (int e = 0; e < NEXP; e++) {
            const float* wr = Wg + e * DDIM;
            float4 w0 = ((const float4*)(wr + c0))[0];
            float4 w1 = ((const float4*)(wr + c0))[1];
            float4 w2 = ((const float4*)(wr + c0 + 512))[0];
            float4 w3 = ((const float4*)(wr + c0 + 512))[1];
            float s = v0.x*w0.x + v0.y*w0.y + v0.z*w0.z + v0.w*w0.w;
            s += v1.x*w1.x + v1.y*w1.y + v1.z*w1.z + v1.w*w1.w;
            s += v2.x*w2.x + v2.y*w2.y + v2.z*w2.z + v2.w*w2.w;
            s += v3.x*w3.x + v3.y*w3.y + v3.z*w3.z + v3.w*w3.w;
            acc[e] = s;
        }
#pragma unroll
        for (int e = 0; e < NEXP; e++) {
#pragma unroll
            for (int o = 32; o > 0; o >>= 1) acc[e] += __shfl_xor(acc[e], o, 64);
        }

        if (lane == 0) {
            float l1 = -1e30f, l2 = -1e30f; int e1 = 0, e2 = 0;
#pragma unroll
            for (int e = 0; e < NEXP; e++) {
                float le = acc[e] + bg[e];
                if (le > l1) { l2 = l1; e2 = e1; l1 = le; e1 = e; }
                else if (le > l2) { l2 = le; e2 = e; }
            }
            float g1 = 1.0f / (1.0f + __expf(l2 - l1));
            float g2 = 1.0f - g1;
            se[lt * 2]     = e1; sg[lt * 2]     = g1;
            se[lt * 2 + 1] = e2; sg[lt * 2 + 1] = g2;
        }
    }
    __syncthreads();

    // one thread per expert: count, reserve range with ONE atomic (per-expert
    // counters padded to separate 64B cache lines -> 8-way parallel TCC atomics)
    if (threadIdx.x < NEXP) {
        int e = threadIdx.x;
        int k = 0;
#pragma unroll 8
        for (int i = 0; i < 64; i++) k += (se[i] == e);
        if (k) {
            int p = atomicAdd(cnt + e * CPAD, k);
            for (int i = 0; i < 64; i++) {
                if (se[i] == e) {
                    tok_list[e * SEG + p]  = (tbase + (i >> 1)) * 2 + (i & 1);
                    gate_list[e * SEG + p] = sg[i];
                    p++;
                }
            }
        }
    }
}

// ---------------- Kernel C: per-expert gathered GEMM, bf16 MFMA ----------------
// r5 verified structure (93.9us): BM=128, BN=256, BK=32, LDS ring of 3 slots
// (A[128][32]+B[256][32] = 24KB/slot, 72KB), prefetch depth 2, ONE s_barrier
// per K-tile, counted vmcnt(3), rotation swizzle slot=(g+(row>>1))&3 with
// inverse rotation pre-applied to the per-lane GLOBAL source address.
// 8 waves (512 thr), each wave owns 64x64 (acc[4][4] = 64 AGPR) -> VGPR 64,
// 2 blocks/CU co-resident (72KB x2 <= 160KB), 2 waves/SIMD intra-block TLP.

__device__ __forceinline__ void stage_tile(const unsigned short* const* sp,
                                           unsigned short* lbase, int wave, int kt) {
    int ko = kt << 5;   // kt * 32 elements
#pragma unroll
    for (int j = 0; j < 3; ++j) {
        __builtin_amdgcn_global_load_lds(
            (const AS1 void*)(sp[j] + ko),
            (AS3 void*)(lbase + (wave * 3 + j) * 512),
            16, 0, 0);
    }
}

__device__ __forceinline__ void tile_mma(const unsigned short* ba, int aoff, int boff,
                                         f32x4 (&acc)[4][4]) {
    bf16x8 af[4], bf[4];
#pragma unroll
    for (int mi = 0; mi < 4; ++mi) af[mi] = *(const bf16x8*)(ba + aoff + mi * 512);
#pragma unroll
    for (int ni = 0; ni < 4; ++ni) bf[ni] = *(const bf16x8*)(ba + boff + ni * 512);
    __builtin_amdgcn_s_setprio(1);
#pragma unroll
    for (int mi = 0; mi < 4; ++mi)
#pragma unroll
        for (int ni = 0; ni < 4; ++ni)
            acc[mi][ni] = __builtin_amdgcn_mfma_f32_16x16x32_bf16(
                af[mi], bf[ni], acc[mi][ni], 0, 0, 0);
    __builtin_amdgcn_s_setprio(0);
}

template<bool STORE>
__global__ __launch_bounds__(512, 2) void moe_gemm(
    const unsigned short* __restrict__ xb, const unsigned short* __restrict__ web,
    const float* __restrict__ be, const int* __restrict__ cnt,
    const int* __restrict__ tok_list, const float* __restrict__ gate_list,
    unsigned short* __restrict__ Sb, float* __restrict__ outa) {

    extern __shared__ __align__(16) unsigned short lbuf[];  // 3 slots x 12288 el = 72 KB
    __shared__ int   tok_s[128];
    __shared__ float gate_s[128];

    // exact-grid: find (expert, m-tile) from flat blockIdx.y via prefix over cnt
    int id = blockIdx.y, e = 0, c = 0;
    while (e < NEXP) {
        c = cnt[e * CPAD];
        int mt = (c + 127) >> 7;
        if (id < mt) break;
        id -= mt; e++;
    }
    if (e == NEXP) return;
    int m0 = id << 7;
    int n0 = blockIdx.x << 8;

    int tid = threadIdx.x;
    int w = tid >> 6, lane = tid & 63;
    int wave_m = w >> 2, wave_n = w & 3;   // 2 x 4 wave grid, each owns 64x64

    if (tid < 128) {
        int r = m0 + tid;
        int rc = min(r, c - 1);
        tok_s[tid]  = tok_list[e * SEG + rc];
        gate_s[tid] = (r < c) ? gate_list[e * SEG + rc] : 0.0f;
    }
    __syncthreads();

    // LDS read offsets (elements); rotation slot for 16-aligned rows = (mrow>>1)&3
    int mrow = lane & 15, q = lane >> 4;
    int ksl  = ((q + (mrow >> 1)) & 3) << 3;
    int aoff = (wave_m * 64 + mrow) * 32 + ksl;           // + mi*512
    int boff = 4096 + (wave_n * 64 + mrow) * 32 + ksl;    // + ni*512

    // staging: chunk ch = wave*3+j; ch<8 -> A rows ch*16+sub; ch>=8 -> B rows
    // (ch-8)*16+sub; per-lane source granule pre-rotated (inverse of LDS slot).
    int g0  = ((lane & 3) - ((lane >> 3) & 3)) & 3;
    int sub = lane >> 2;
    const unsigned short* sp[3];
#pragma unroll
    for (int j = 0; j < 3; ++j) {
        int ch = w * 3 + j;
        int arow = min((ch << 4) + sub, 127);
        int brow = ((ch - 8) << 4) + sub;
        const unsigned short* pa = xb + (size_t)(tok_s[arow] >> 1) * DDIM + g0 * 8;
        const unsigned short* pb = web + ((size_t)e << 20) +
                                   (size_t)(n0 + brow) * DDIM + g0 * 8;
        sp[j] = (ch < 8) ? pa : pb;
    }

    f32x4 acc[4][4];
#pragma unroll
    for (int mi = 0; mi < 4; ++mi)
#pragma unroll
        for (int ni = 0; ni < 4; ++ni) acc[mi][ni] = (f32x4){0.f, 0.f, 0.f, 0.f};

    // ---- prologue: stage K-tiles 0,1 (3 loads each per wave; 6 outstanding) ----
    stage_tile(sp, lbuf,         w, 0);
    stage_tile(sp, lbuf + 12288, w, 1);

    // ---- main loop: K-tiles 0..29, stage kt+2, wait vmcnt(3) (tile kt done,
    //      tile kt+1's 3 loads stay in flight across the barrier) ----
    for (int kb = 0; kb < 10; ++kb) {
#pragma unroll
        for (int u = 0; u < 3; ++u) {
            int kt = kb * 3 + u;
            asm volatile("s_waitcnt vmcnt(3)" ::: "memory");
            __builtin_amdgcn_s_barrier();
            asm volatile("" ::: "memory");
            stage_tile(sp, lbuf + ((u + 2) % 3) * 12288, w, kt + 2);
            tile_mma(lbuf + u * 12288, aoff, boff, acc);
        }
    }
    // ---- epilogue tiles 30 (slot 0) and 31 (slot 1) ----
    asm volatile("s_waitcnt vmcnt(3)" ::: "memory");
    __builtin_amdgcn_s_barrier();
    asm volatile("" ::: "memory");
    tile_mma(lbuf, aoff, boff, acc);

    asm volatile("s_waitcnt vmcnt(0)" ::: "memory");
    __builtin_amdgcn_s_barrier();
    asm volatile("" ::: "memory");
    tile_mma(lbuf + 12288, aoff, boff, acc);

    if (STORE) {
        // ---- stage C-tile (gate*(acc+bias), bf16) into LDS, XOR-swizzled ----
        __syncthreads();
#pragma unroll
        for (int ni = 0; ni < 4; ++ni) {
            int col = wave_n * 64 + ni * 16 + mrow;       // tile-local col (0..255)
            float bias = be[e * DDIM + n0 + col];
            int cg = col >> 3, cl = col & 7;
#pragma unroll
            for (int mi = 0; mi < 4; ++mi) {
#pragma unroll
                for (int r = 0; r < 4; ++r) {
                    int row = wave_m * 64 + mi * 16 + q * 4 + r;   // 0..127
                    lbuf[row * 256 + ((cg ^ (row & 7)) << 3) + cl] =
                        f2bf(gate_s[row] * (acc[mi][ni][r] + bias));
                }
            }
        }
        __syncthreads();
        // ---- coalesced 16B stores: 128x32 granules / 512 threads = 8 iters ----
#pragma unroll
        for (int j = 0; j < 8; ++j) {
            int t = j * 512 + tid;
            int row = t >> 5, gc = t & 31;
            u16x8 vv = *(const u16x8*)&lbuf[row * 256 + ((gc ^ (row & 7)) << 3)];
            if (m0 + row < c)
                *(u16x8*)(Sb + (size_t)tok_s[row] * DDIM + n0 + gc * 8) = vv;
        }
    } else {
        __syncthreads();
#pragma unroll
        for (int ni = 0; ni < 4; ++ni) {
            int col = n0 + wave_n * 64 + ni * 16 + mrow;
            float bias = be[e * DDIM + col];
#pragma unroll
            for (int mi = 0; mi < 4; ++mi) {
#pragma unroll
                for (int r = 0; r < 4; ++r) {
                    int rl = wave_m * 64 + mi * 16 + q * 4 + r;
                    if (m0 + rl < c)
                        atomicAdd(outa + (size_t)(tok_s[rl] >> 1) * DDIM + col,
                                  gate_s[rl] * (acc[mi][ni][r] + bias));
                }
            }
        }
    }
}

// ---------------- Kernel D: combine the two slot rows per token ----------------
// out[t] = S[2t] + S[2t+1]; nontemporal loads (S is read-once, no-allocate) and
// nontemporal stores for out (never re-read on device).
__global__ void combine(const unsigned short* __restrict__ S, float* __restrict__ out) {
    size_t i = (size_t)blockIdx.x * 256 + threadIdx.x;
    size_t t = i >> 7;
    size_t g = i & 127;
    const u16x8* r0 = (const u16x8*)(S + t * 2 * DDIM) + g;
    const u16x8* r1 = (const u16x8*)(S + (t * 2 + 1) * DDIM) + g;
    u16x8 a = __builtin_nontemporal_load(r0);
    u16x8 b = __builtin_nontemporal_load(r1);
    f32x4 o0, o1;
#pragma unroll
    for (int k = 0; k < 4; k++) o0[k] = bf2f(a[k]) + bf2f(b[k]);
#pragma unroll
    for (int k = 0; k < 4; k++) o1[k] = bf2f(a[4 + k]) + bf2f(b[4 + k]);
    f32x4* op = (f32x4*)(out + t * DDIM + g * 8);
    __builtin_nontemporal_store(o0, op);
    __builtin_nontemporal_store(o1, op + 1);
}

extern "C" void kernel_launch(void* const* d_in, const int* in_sizes, int n_in,
                              void* d_out, int out_size, void* d_ws, size_t ws_size,
                              hipStream_t stream) {
    const float* x  = (const float*)d_in[0];
    const float* Wg = (const float*)d_in[1];
    const float* bg = (const float*)d_in[2];
    const float* We = (const float*)d_in[3];
    const float* be = (const float*)d_in[4];
    float* out = (float*)d_out;

    char* ws = (char*)d_ws;
    unsigned short* xb  = (unsigned short*)ws;                          // 32 MB
    unsigned short* web = (unsigned short*)(ws + 33554432);             // 16 MB
    int*   tok_list  = (int*)(ws + 33554432 + 16777216);                // 512 KB
    float* gate_list = (float*)(ws + 33554432 + 16777216 + 524288);     // 512 KB
    int*   cnt       = (int*)(ws + 33554432 + 16777216 + 1048576);      // 8 x 64B padded
    unsigned short* S = (unsigned short*)(ws + 52428800);               // 67.1 MB

    const size_t NEED = 52428800ull + (size_t)32768 * DDIM * 2;         // ~119.5 MB

    // one-time opt-in for 72KB dynamic LDS
    static bool attr_done = false;
    if (!attr_done) {
        hipFuncSetAttribute(reinterpret_cast<const void*>(moe_gemm<true>),
                            hipFuncAttributeMaxDynamicSharedMemorySize, 73728);
        hipFuncSetAttribute(reinterpret_cast<const void*>(moe_gemm<false>),
                            hipFuncAttributeMaxDynamicSharedMemorySize, 73728);
        attr_done = true;
    }

    hipMemsetAsync(cnt, 0, NEXP * CPAD * sizeof(int), stream);

    // 512 gating blocks + 2048 convert blocks in one dispatch
    prep<<<2560, 512, 0, stream>>>(x, Wg, bg, We, xb, web, cnt, tok_list, gate_list);

    if (ws_size >= NEED) {
        // grid.y = 264: max total m-tiles = 32768/128 + 8 ceil-partials; x = 4 n-tiles
        moe_gemm<true><<<dim3(4, 264), 512, 73728, stream>>>(
            xb, web, be, cnt, tok_list, gate_list, S, nullptr);
        combine<<<8192, 256, 0, stream>>>(S, out);
    } else {
        hipMemsetAsync(d_out, 0, (size_t)out_size * sizeof(float), stream);
        moe_gemm<false><<<dim3(4, 264), 512, 73728, stream>>>(
            xb, web, be, cnt, tok_list, gate_list, nullptr, out);
    }
}

// Round 10
// 271.664 us; speedup vs baseline: 1.0690x; 1.0285x over previous
//
#include <hip/hip_runtime.h>
#include <hip/hip_bf16.h>
#include <stdint.h>

#define DDIM 1024
#define NEXP 8
#define SEG  16384   // per-expert token capacity (worst case: every token picks it)
#define CPAD 16      // cnt stride in ints: one 64B cache line per expert counter

typedef __attribute__((ext_vector_type(8))) short bf16x8;
typedef __attribute__((ext_vector_type(4))) float f32x4;
typedef __attribute__((ext_vector_type(8))) unsigned short u16x8;

#define AS1 __attribute__((address_space(1)))
#define AS3 __attribute__((address_space(3)))

__device__ __forceinline__ unsigned short f2bf(float f) {
    union { float f; unsigned int u; } v; v.f = f;
    unsigned int u = v.u;
    return (unsigned short)((u + 0x7FFFu + ((u >> 16) & 1u)) >> 16);
}
__device__ __forceinline__ float bf2f(unsigned short h) {
    union { unsigned int u; float f; } v; v.u = ((unsigned int)h) << 16;
    return v.f;
}

// ---------------- Kernel A (fused): We fp32->bf16 convert + gating/routing ----
__global__ __launch_bounds__(512) void prep(
    const float* __restrict__ x, const float* __restrict__ Wg,
    const float* __restrict__ bg, const float* __restrict__ We,
    unsigned short* __restrict__ xb, unsigned short* __restrict__ web,
    int* __restrict__ cnt, int* __restrict__ tok_list,
    float* __restrict__ gate_list) {

    __shared__ int   se[64];   // entry = local_token*2 + slot
    __shared__ float sg[64];

    if (blockIdx.x >= 512) {
        size_t idx = ((size_t)(blockIdx.x - 512) * 512 + threadIdx.x) * 8;
        const f32x4* p = (const f32x4*)(We + idx);
        f32x4 a = __builtin_nontemporal_load(p);
        f32x4 b = __builtin_nontemporal_load(p + 1);
        u16x8 h;
        h[0] = f2bf(a[0]); h[1] = f2bf(a[1]); h[2] = f2bf(a[2]); h[3] = f2bf(a[3]);
        h[4] = f2bf(b[0]); h[5] = f2bf(b[1]); h[6] = f2bf(b[2]); h[7] = f2bf(b[3]);
        *(u16x8*)(web + idx) = h;
        return;
    }

    int wave = threadIdx.x >> 6, lane = threadIdx.x & 63;
    int tbase = blockIdx.x * 32;

#pragma unroll
    for (int i = 0; i < 4; i++) {
        int lt = wave * 4 + i;
        int t = tbase + lt;
        const float* xr = x + (size_t)t * DDIM;
        int c0 = lane * 8;

        float4 v0 = ((const float4*)(xr + c0))[0];
        float4 v1 = ((const float4*)(xr + c0))[1];
        float4 v2 = ((const float4*)(xr + c0 + 512))[0];
        float4 v3 = ((const float4*)(xr + c0 + 512))[1];

        u16x8 h0, h1;
        h0[0] = f2bf(v0.x); h0[1] = f2bf(v0.y); h0[2] = f2bf(v0.z); h0[3] = f2bf(v0.w);
        h0[4] = f2bf(v1.x); h0[5] = f2bf(v1.y); h0[6] = f2bf(v1.z); h0[7] = f2bf(v1.w);
        h1[0] = f2bf(v2.x); h1[1] = f2bf(v2.y); h1[2] = f2bf(v2.z); h1[3] = f2bf(v2.w);
        h1[4] = f2bf(v3.x); h1[5] = f2bf(v3.y); h1[6] = f2bf(v3.z); h1[7] = f2bf(v3.w);
        *(u16x8*)(xb + (size_t)t * DDIM + c0) = h0;
        *(u16x8*)(xb + (size_t)t * DDIM + c0 + 512) = h1;

        float acc[NEXP];
#pragma unroll
        for (int e = 0; e < NEXP; e++) {
            const float* wr = Wg + e * DDIM;
            float4 w0 = ((const float4*)(wr + c0))[0];
            float4 w1 = ((const float4*)(wr + c0))[1];
            float4 w2 = ((const float4*)(wr + c0 + 512))[0];
            float4 w3 = ((const float4*)(wr + c0 + 512))[1];
            float s = v0.x*w0.x + v0.y*w0.y + v0.z*w0.z + v0.w*w0.w;
            s += v1.x*w1.x + v1.y*w1.y + v1.z*w1.z + v1.w*w1.w;
            s += v2.x*w2.x + v2.y*w2.y + v2.z*w2.z + v2.w*w2.w;
            s += v3.x*w3.x + v3.y*w3.y + v3.z*w3.z + v3.w*w3.w;
            acc[e] = s;
        }
#pragma unroll
        for (int e = 0; e < NEXP; e++) {
#pragma unroll
            for (int o = 32; o > 0; o >>= 1) acc[e] += __shfl_xor(acc[e], o, 64);
        }

        if (lane == 0) {
            float l1 = -1e30f, l2 = -1e30f; int e1 = 0, e2 = 0;
#pragma unroll
            for (int e = 0; e < NEXP; e++) {
                float le = acc[e] + bg[e];
                if (le > l1) { l2 = l1; e2 = e1; l1 = le; e1 = e; }
                else if (le > l2) { l2 = le; e2 = e; }
            }
            float g1 = 1.0f / (1.0f + __expf(l2 - l1));
            float g2 = 1.0f - g1;
            se[lt * 2]     = e1; sg[lt * 2]     = g1;
            se[lt * 2 + 1] = e2; sg[lt * 2 + 1] = g2;
        }
    }
    __syncthreads();

    // one thread per expert: count, reserve range with ONE atomic (per-expert
    // counters on separate 64B cache lines)
    if (threadIdx.x < NEXP) {
        int e = threadIdx.x;
        int k = 0;
#pragma unroll 8
        for (int i = 0; i < 64; i++) k += (se[i] == e);
        if (k) {
            int p = atomicAdd(cnt + e * CPAD, k);
            for (int i = 0; i < 64; i++) {
                if (se[i] == e) {
                    tok_list[e * SEG + p]  = (tbase + (i >> 1)) * 2 + (i & 1);
                    gate_list[e * SEG + p] = sg[i];
                    p++;
                }
            }
        }
    }
}

// ---------------- Kernel C: per-expert gathered GEMM, bf16 MFMA ----------------
// r5 verified structure (93.9us): BM=128, BN=256, BK=32, LDS ring of 3 slots
// (A[128][32]+B[256][32] = 24KB/slot, 72KB), prefetch depth 2, ONE s_barrier
// per K-tile, counted vmcnt(3), rotation swizzle slot=(g+(row>>1))&3 with
// inverse rotation pre-applied to the per-lane GLOBAL source address.
// 8 waves (512 thr), each wave owns 64x64 (acc[4][4] = 64 AGPR) -> VGPR 64,
// 2 blocks/CU co-resident (72KB x2 <= 160KB), 2 waves/SIMD intra-block TLP.
// NEW vs r5/r8: bijective XCD chunk swizzle computed against the device-side
// REAL tile total (m204 form): each XCD gets a contiguous run of m-tiles x 4
// n-tiles within ~1-2 experts -> that expert's web panels (2MB) stay resident
// in the XCD's 4MB L2; A-panels reused across the 4 consecutive n-tiles.
// Empty trailing fids stay round-robin balanced across XCDs.

__device__ __forceinline__ void stage_tile(const unsigned short* const* sp,
                                           unsigned short* lbase, int wave, int kt) {
    int ko = kt << 5;   // kt * 32 elements
#pragma unroll
    for (int j = 0; j < 3; ++j) {
        __builtin_amdgcn_global_load_lds(
            (const AS1 void*)(sp[j] + ko),
            (AS3 void*)(lbase + (wave * 3 + j) * 512),
            16, 0, 0);
    }
}

__device__ __forceinline__ void tile_mma(const unsigned short* ba, int aoff, int boff,
                                         f32x4 (&acc)[4][4]) {
    bf16x8 af[4], bf[4];
#pragma unroll
    for (int mi = 0; mi < 4; ++mi) af[mi] = *(const bf16x8*)(ba + aoff + mi * 512);
#pragma unroll
    for (int ni = 0; ni < 4; ++ni) bf[ni] = *(const bf16x8*)(ba + boff + ni * 512);
    __builtin_amdgcn_s_setprio(1);
#pragma unroll
    for (int mi = 0; mi < 4; ++mi)
#pragma unroll
        for (int ni = 0; ni < 4; ++ni)
            acc[mi][ni] = __builtin_amdgcn_mfma_f32_16x16x32_bf16(
                af[mi], bf[ni], acc[mi][ni], 0, 0, 0);
    __builtin_amdgcn_s_setprio(0);
}

template<bool STORE>
__global__ __launch_bounds__(512, 2) void moe_gemm(
    const unsigned short* __restrict__ xb, const unsigned short* __restrict__ web,
    const float* __restrict__ be, const int* __restrict__ cnt,
    const int* __restrict__ tok_list, const float* __restrict__ gate_list,
    unsigned short* __restrict__ Sb, float* __restrict__ outa) {

    extern __shared__ __align__(16) unsigned short lbuf[];  // 3 slots x 12288 el = 72 KB
    __shared__ int   tok_s[128];
    __shared__ float gate_s[128];

    // ---- bijective XCD chunk swizzle over the REAL tile total ----
    int fid = blockIdx.x + blockIdx.y * 4;          // dispatch id, 0..1055
    int total = 0;
#pragma unroll
    for (int e2 = 0; e2 < NEXP; ++e2)
        total += ((cnt[e2 * CPAD] + 127) >> 7) << 2;   // m-tiles * 4 n-tiles
    if (fid >= total) return;
    int q8 = total >> 3, r8 = total & 7;
    int xcd = fid & 7, sfid = fid >> 3;
    int L = (xcd < r8 ? xcd * (q8 + 1) : r8 * (q8 + 1) + (xcd - r8) * q8) + sfid;

    // decode L: expert-major, m-tile, n fastest (4 n-tiles of an m-tile adjacent)
    int e = 0, c = 0, rem = L;
    while (e < NEXP) {
        c = cnt[e * CPAD];
        int t_e = ((c + 127) >> 7) << 2;
        if (rem < t_e) break;
        rem -= t_e; e++;
    }
    if (e == NEXP) return;
    int m0 = (rem >> 2) << 7;
    int n0 = (rem & 3) << 8;

    int tid = threadIdx.x;
    int w = tid >> 6, lane = tid & 63;
    int wave_m = w >> 2, wave_n = w & 3;   // 2 x 4 wave grid, each owns 64x64

    if (tid < 128) {
        int r = m0 + tid;
        int rc = min(r, c - 1);
        tok_s[tid]  = tok_list[e * SEG + rc];
        gate_s[tid] = (r < c) ? gate_list[e * SEG + rc] : 0.0f;
    }
    __syncthreads();

    // LDS read offsets (elements); rotation slot for 16-aligned rows = (mrow>>1)&3
    int mrow = lane & 15, q = lane >> 4;
    int ksl  = ((q + (mrow >> 1)) & 3) << 3;
    int aoff = (wave_m * 64 + mrow) * 32 + ksl;           // + mi*512
    int boff = 4096 + (wave_n * 64 + mrow) * 32 + ksl;    // + ni*512

    // staging: chunk ch = wave*3+j; ch<8 -> A rows ch*16+sub; ch>=8 -> B rows
    // (ch-8)*16+sub; per-lane source granule pre-rotated (inverse of LDS slot).
    int g0  = ((lane & 3) - ((lane >> 3) & 3)) & 3;
    int sub = lane >> 2;
    const unsigned short* sp[3];
#pragma unroll
    for (int j = 0; j < 3; ++j) {
        int ch = w * 3 + j;
        int arow = min((ch << 4) + sub, 127);
        int brow = ((ch - 8) << 4) + sub;
        const unsigned short* pa = xb + (size_t)(tok_s[arow] >> 1) * DDIM + g0 * 8;
        const unsigned short* pb = web + ((size_t)e << 20) +
                                   (size_t)(n0 + brow) * DDIM + g0 * 8;
        sp[j] = (ch < 8) ? pa : pb;
    }

    f32x4 acc[4][4];
#pragma unroll
    for (int mi = 0; mi < 4; ++mi)
#pragma unroll
        for (int ni = 0; ni < 4; ++ni) acc[mi][ni] = (f32x4){0.f, 0.f, 0.f, 0.f};

    // ---- prologue: stage K-tiles 0,1 (3 loads each per wave; 6 outstanding) ----
    stage_tile(sp, lbuf,         w, 0);
    stage_tile(sp, lbuf + 12288, w, 1);

    // ---- main loop: K-tiles 0..29, stage kt+2, wait vmcnt(3) (tile kt done,
    //      tile kt+1's 3 loads stay in flight across the barrier) ----
    for (int kb = 0; kb < 10; ++kb) {
#pragma unroll
        for (int u = 0; u < 3; ++u) {
            int kt = kb * 3 + u;
            asm volatile("s_waitcnt vmcnt(3)" ::: "memory");
            __builtin_amdgcn_s_barrier();
            asm volatile("" ::: "memory");
            stage_tile(sp, lbuf + ((u + 2) % 3) * 12288, w, kt + 2);
            tile_mma(lbuf + u * 12288, aoff, boff, acc);
        }
    }
    // ---- epilogue tiles 30 (slot 0) and 31 (slot 1) ----
    asm volatile("s_waitcnt vmcnt(3)" ::: "memory");
    __builtin_amdgcn_s_barrier();
    asm volatile("" ::: "memory");
    tile_mma(lbuf, aoff, boff, acc);

    asm volatile("s_waitcnt vmcnt(0)" ::: "memory");
    __builtin_amdgcn_s_barrier();
    asm volatile("" ::: "memory");
    tile_mma(lbuf + 12288, aoff, boff, acc);

    if (STORE) {
        // ---- stage C-tile (gate*(acc+bias), bf16) into LDS, XOR-swizzled ----
        __syncthreads();
#pragma unroll
        for (int ni = 0; ni < 4; ++ni) {
            int col = wave_n * 64 + ni * 16 + mrow;       // tile-local col (0..255)
            float bias = be[e * DDIM + n0 + col];
            int cg = col >> 3, cl = col & 7;
#pragma unroll
            for (int mi = 0; mi < 4; ++mi) {
#pragma unroll
                for (int r = 0; r < 4; ++r) {
                    int row = wave_m * 64 + mi * 16 + q * 4 + r;   // 0..127
                    lbuf[row * 256 + ((cg ^ (row & 7)) << 3) + cl] =
                        f2bf(gate_s[row] * (acc[mi][ni][r] + bias));
                }
            }
        }
        __syncthreads();
        // ---- coalesced 16B stores: 128x32 granules / 512 threads = 8 iters ----
#pragma unroll
        for (int j = 0; j < 8; ++j) {
            int t = j * 512 + tid;
            int row = t >> 5, gc = t & 31;
            u16x8 vv = *(const u16x8*)&lbuf[row * 256 + ((gc ^ (row & 7)) << 3)];
            if (m0 + row < c)
                *(u16x8*)(Sb + (size_t)tok_s[row] * DDIM + n0 + gc * 8) = vv;
        }
    } else {
        __syncthreads();
#pragma unroll
        for (int ni = 0; ni < 4; ++ni) {
            int col = n0 + wave_n * 64 + ni * 16 + mrow;
            float bias = be[e * DDIM + col];
#pragma unroll
            for (int mi = 0; mi < 4; ++mi) {
#pragma unroll
                for (int r = 0; r < 4; ++r) {
                    int rl = wave_m * 64 + mi * 16 + q * 4 + r;
                    if (m0 + rl < c)
                        atomicAdd(outa + (size_t)(tok_s[rl] >> 1) * DDIM + col,
                                  gate_s[rl] * (acc[mi][ni][r] + bias));
                }
            }
        }
    }
}

// ---------------- Kernel D: combine the two slot rows per token ----------------
// out[t] = S[2t] + S[2t+1]; plain loads (S may be L2/L3-hot), nontemporal
// stores for out (never re-read on device).
__global__ void combine(const unsigned short* __restrict__ S, float* __restrict__ out) {
    size_t i = (size_t)blockIdx.x * 256 + threadIdx.x;
    size_t t = i >> 7;
    size_t g = i & 127;
    const u16x8* r0 = (const u16x8*)(S + t * 2 * DDIM) + g;
    const u16x8* r1 = (const u16x8*)(S + (t * 2 + 1) * DDIM) + g;
    u16x8 a = *r0;
    u16x8 b = *r1;
    f32x4 o0, o1;
#pragma unroll
    for (int k = 0; k < 4; k++) o0[k] = bf2f(a[k]) + bf2f(b[k]);
#pragma unroll
    for (int k = 0; k < 4; k++) o1[k] = bf2f(a[4 + k]) + bf2f(b[4 + k]);
    f32x4* op = (f32x4*)(out + t * DDIM + g * 8);
    __builtin_nontemporal_store(o0, op);
    __builtin_nontemporal_store(o1, op + 1);
}

extern "C" void kernel_launch(void* const* d_in, const int* in_sizes, int n_in,
                              void* d_out, int out_size, void* d_ws, size_t ws_size,
                              hipStream_t stream) {
    const float* x  = (const float*)d_in[0];
    const float* Wg = (const float*)d_in[1];
    const float* bg = (const float*)d_in[2];
    const float* We = (const float*)d_in[3];
    const float* be = (const float*)d_in[4];
    float* out = (float*)d_out;

    char* ws = (char*)d_ws;
    unsigned short* xb  = (unsigned short*)ws;                          // 32 MB
    unsigned short* web = (unsigned short*)(ws + 33554432);             // 16 MB
    int*   tok_list  = (int*)(ws + 33554432 + 16777216);                // 512 KB
    float* gate_list = (float*)(ws + 33554432 + 16777216 + 524288);     // 512 KB
    int*   cnt       = (int*)(ws + 33554432 + 16777216 + 1048576);      // 8 x 64B padded
    unsigned short* S = (unsigned short*)(ws + 52428800);               // 67.1 MB

    const size_t NEED = 52428800ull + (size_t)32768 * DDIM * 2;         // ~119.5 MB

    // one-time opt-in for 72KB dynamic LDS
    static bool attr_done = false;
    if (!attr_done) {
        hipFuncSetAttribute(reinterpret_cast<const void*>(moe_gemm<true>),
                            hipFuncAttributeMaxDynamicSharedMemorySize, 73728);
        hipFuncSetAttribute(reinterpret_cast<const void*>(moe_gemm<false>),
                            hipFuncAttributeMaxDynamicSharedMemorySize, 73728);
        attr_done = true;
    }

    hipMemsetAsync(cnt, 0, NEXP * CPAD * sizeof(int), stream);

    // 512 gating blocks + 2048 convert blocks in one dispatch
    prep<<<2560, 512, 0, stream>>>(x, Wg, bg, We, xb, web, cnt, tok_list, gate_list);

    if (ws_size >= NEED) {
        // grid = 1056 dispatch slots (4 x 264); real tiles swizzled device-side
        moe_gemm<true><<<dim3(4, 264), 512, 73728, stream>>>(
            xb, web, be, cnt, tok_list, gate_list, S, nullptr);
        combine<<<8192, 256, 0, stream>>>(S, out);
    } else {
        hipMemsetAsync(d_out, 0, (size_t)out_size * sizeof(float), stream);
        moe_gemm<false><<<dim3(4, 264), 512, 73728, stream>>>(
            xb, web, be, cnt, tok_list, gate_list, nullptr, out);
    }
}